// Round 1
// 445.640 us; speedup vs baseline: 1.0008x; 1.0008x over previous
//
#include <hip/hip_runtime.h>

namespace {

constexpr int U = 128;
constexpr int ROW_IN = 4 * U;    // 512 floats per x1 row
constexpr int ROW_OUT = 11 * U;  // 1408 floats per out row
constexpr int R = 4;             // rows per block
constexpr float INV_SQRT3 = 0.57735026918962576f;  // 1/sqrt(3)
constexpr float INV_SQRT2 = 0.70710678118654752f;  // 1/sqrt(2)

// Stage input and output tiles in LDS so ALL HBM traffic is contiguous
// dwordx4. The previous version issued 5 interleaved narrow write streams
// per wave (dword + 12B F3 stores) -> ~2.3 TB/s effective. The fill kernel
// on the same buffers hits 6.4 TB/s with one sequential dwordx4 stream;
// this kernel now produces the same access shape.
__global__ __launch_bounds__(256) void tp_kernel(
    const float* __restrict__ x1, const float* __restrict__ x2,
    const float* __restrict__ w, float* __restrict__ out, int nrows) {
  __shared__ float sin_[R * ROW_IN];   // 8 KB
  __shared__ float sout[R * ROW_OUT];  // 22.5 KB

  const int tid = threadIdx.x;
  const int row0 = blockIdx.x * R;
  const int rows_here = min(R, nrows - row0);
  if (rows_here <= 0) return;

  // ---- phase 1: x1 rows -> LDS via dwordx4 (coalesced, sequential) ----
  {
    const float4* g = reinterpret_cast<const float4*>(x1 + (size_t)row0 * ROW_IN);
    float4* s = reinterpret_cast<float4*>(sin_);
    const int n4 = rows_here * (ROW_IN / 4);  // <= 512
    for (int idx = tid; idx < n4; idx += 256) s[idx] = g[idx];
  }

  // weights: 5 dword loads per thread, once per block; L1/L2-resident (2.5 KB)
  const int u = tid & (U - 1);
  const float w0 = w[u];
  const float w1 = w[U + u];
  const float w2 = w[2 * U + u];
  const float w3 = w[3 * U + u];
  const float w4 = w[4 * U + u];

  __syncthreads();

  // ---- phase 2: compute into sout ----
  // 256 threads = 2 rows x 128 channels per pass; R/2 passes.
  // LDS read patterns: stride-1 and stride-3 words -> <=2-way bank
  // aliasing (free on CDNA4, 64 lanes / 32 banks).
  const int rr = tid >> 7;  // 0 or 1
#pragma unroll
  for (int p = 0; p < R / 2; ++p) {
    const int r = 2 * p + rr;
    if (r < rows_here) {
      const float* xr = sin_ + r * ROW_IN;
      const float s0 = xr[u];
      const float s1x = xr[U + 3 * u];
      const float s1y = xr[U + 3 * u + 1];
      const float s1z = xr[U + 3 * u + 2];
      // 16B broadcast per row (uniform address within each wave): L1 hit
      const float4 y = reinterpret_cast<const float4*>(x2)[row0 + r];

      float* o = sout + r * ROW_OUT;
      // o0[u] = w0 * s0 * y0
      o[u] = w0 * s0 * y.x;
      // o1[u,i] = w1 * s0 * y1[i]
      const float t1 = w1 * s0;
      o[U + 3 * u] = t1 * y.y;
      o[U + 3 * u + 1] = t1 * y.z;
      o[U + 3 * u + 2] = t1 * y.w;
      // o2[u,i] = w2 * s1[i] * y0
      const float t2 = w2 * y.x;
      o[4 * U + 3 * u] = t2 * s1x;
      o[4 * U + 3 * u + 1] = t2 * s1y;
      o[4 * U + 3 * u + 2] = t2 * s1z;
      // o3[u] = w3 * dot(s1, y1) / sqrt(3)
      o[7 * U + u] = w3 * (s1x * y.y + s1y * y.z + s1z * y.w) * INV_SQRT3;
      // o4[u,k] = w4 * cross(s1, y1)[k] / sqrt(2)
      const float t4 = w4 * INV_SQRT2;
      o[8 * U + 3 * u] = t4 * (s1y * y.w - s1z * y.z);
      o[8 * U + 3 * u + 1] = t4 * (s1z * y.y - s1x * y.w);
      o[8 * U + 3 * u + 2] = t4 * (s1x * y.z - s1y * y.y);
    }
  }

  __syncthreads();

  // ---- phase 3: sout -> out via dwordx4, one contiguous stream/block ----
  {
    float4* g = reinterpret_cast<float4*>(out + (size_t)row0 * ROW_OUT);
    const float4* s = reinterpret_cast<const float4*>(sout);
    const int n4 = rows_here * (ROW_OUT / 4);  // <= 1408
    for (int idx = tid; idx < n4; idx += 256) g[idx] = s[idx];
  }
}

}  // namespace

extern "C" void kernel_launch(void* const* d_in, const int* in_sizes, int n_in,
                              void* d_out, int out_size, void* d_ws, size_t ws_size,
                              hipStream_t stream) {
  const float* x1 = (const float*)d_in[0];
  const float* x2 = (const float*)d_in[1];
  const float* w  = (const float*)d_in[2];
  float* out = (float*)d_out;

  const int nrows = in_sizes[0] / (4 * U);  // B
  const int grid = (nrows + R - 1) / R;     // 16384 blocks at B=65536
  const int block = 256;

  hipLaunchKernelGGL(tp_kernel, dim3(grid), dim3(block), 0, stream,
                     x1, x2, w, out, nrows);
}